// Round 15
// baseline (51.475 us; speedup 1.0000x reference)
//
#include <hip/hip_runtime.h>
#include <math.h>

#define CLIPV 1.0e4f
#define DT 0.1f
#define JITTER 1.0e-5f
#define MIN_SCALE 1.0e-4f

// nan_to_num(nan=0, posinf=CLIP, neginf=-CLIP) then clip(-CLIP, CLIP)
__device__ __forceinline__ float sanv(float x) {
    if (__builtin_isnan(x)) return 0.0f;
    return fminf(fmaxf(x, -CLIPV), CLIPV);
}

struct Params {
    float im00, im01, im11;   // sanitized inverse entries
    float nldh;               // -0.5 * log_det
    float dr0, dr1;           // sanitized drift
    float sc;                 // softplus(bsr) + MIN_SCALE
    float repA, repB, repD;   // repaired matrix (for output 3)
};

// Exact reference semantics for the per-(t,i,j) block parameters.
__device__ void compute_params(
        const float* __restrict__ means, const float* __restrict__ covs,
        const float* __restrict__ bsr, int t, int i, int j, Params& O) {
    float mi0 = sanv(means[(t * 2 + i) * 2 + 0]);
    float mi1 = sanv(means[(t * 2 + i) * 2 + 1]);
    float d0, d1;
    if (i == j) { d0 = DT * mi0; d1 = DT * mi1; }
    else {
        float mj0 = sanv(means[(t * 2 + j) * 2 + 0]);
        float mj1 = sanv(means[(t * 2 + j) * 2 + 1]);
        d0 = DT * (mi0 - mj0); d1 = DT * (mi1 - mj1);
    }
    O.dr0 = sanv(d0); O.dr1 = sanv(d1);

    const float* pi = covs + (t * 2 + i) * 4;
    float ra = sanv(pi[0]);
    float rb = 0.5f * (sanv(pi[1]) + sanv(pi[2]));
    float rd = sanv(pi[3]);
    if (i != j) {
        const float* pj = covs + (t * 2 + j) * 4;
        ra += sanv(pj[0]);
        rb += 0.5f * (sanv(pj[1]) + sanv(pj[2]));
        rd += sanv(pj[3]);
    }
    const float c2 = 2.0f * DT * DT;
    float A = sanv(1.0f + c2 * ra + JITTER);
    float B = sanv(c2 * rb);
    float D = sanv(1.0f + c2 * rd + JITTER);

    float diag_scale = fmaxf(0.5f * (fabsf(A) + fabsf(D)), 1.0f);
    const float j0 = 1e-5f; // max(JITTER, 1e-6)
    float invA = 0.f, invB = 0.f, invD = 0.f, logdet = 0.f;
    float repA = 0.f, repB = 0.f, repD = 0.f;
    bool found = false;
    float jit = j0;
    for (int k = 0; k < 8; ++k) {
        float add = jit * diag_scale;
        float a = sanv(A + add), b = B, d = sanv(D + add);
        float det = a * d - b * b;   // chol PD test for 2x2: a>0 && det>0
        if (a > 0.0f && det > 0.0f && __builtin_isfinite(det)) {
            repA = a; repB = b; repD = d;
            logdet = logf(det);      // == 2*sum(log(diag(chol)))
            float rdet = 1.0f / det;
            invA = sanv(d * rdet); invB = sanv(-b * rdet); invD = sanv(a * rdet);
            found = true;
            break;
        }
        jit *= 10.0f;
    }
    if (!found) {
        float jfin = j0 * 1.0e8f; // j0 * 10^MAX_TRIES
        float add = jfin * diag_scale;
        float sd0 = fmaxf(fabsf(A), add + 1e-4f);
        float sd1 = fmaxf(fabsf(D), add + 1e-4f);
        repA = sanv(sd0 + add); repB = 0.0f; repD = sanv(sd1 + add);
        float dfb0 = fmaxf(repA, 1e-6f), dfb1 = fmaxf(repD, 1e-6f);
        invA = sanv(1.0f / dfb0); invB = 0.0f; invD = sanv(1.0f / dfb1);
        logdet = logf(dfb0) + logf(dfb1);
    }
    if (__builtin_isnan(logdet)) logdet = 0.0f;
    else if (__builtin_isinf(logdet)) logdet = logdet > 0.0f ? 20.0f : -20.0f;

    float x = bsr[i * 2 + j];
    float sp = fmaxf(x, 0.0f) + log1pf(expf(-fabsf(x)));
    O.sc = sp + MIN_SCALE;
    O.im00 = invA; O.im01 = invB; O.im11 = invD;
    O.nldh = -0.5f * logdet;
    O.repA = repA; O.repB = repB; O.repD = repD;
}

// ---------------- PROBE: store-only fill of the trans region --------------
// Mirrors __amd_rocclr_fillBufferAligned structure: grid-stride, minimal
// VGPRs, dependency-free dwordx4 stores. Measures the pure-store floor for
// this 134 MB (L3-fitting) buffer. Output correctness unaffected: the real
// kernel overwrites every byte afterwards.
__global__ __launch_bounds__(256) void fill_probe_kernel(float4* __restrict__ p,
                                                         int n4) {
    float4 z = {0.f, 0.f, 0.f, 0.f};
    int stride = gridDim.x * blockDim.x;
    for (int k = blockIdx.x * blockDim.x + threadIdx.x; k < n4; k += stride)
        p[k] = z;
}

// ---------------- Fused: one wave per FOUR consecutive rows ---------------
// Identical to round 14.
__global__ __launch_bounds__(256) void row4_fused_kernel(
        const float* __restrict__ means, const float* __restrict__ covs,
        const float* __restrict__ site, const float* __restrict__ bsr,
        const float* __restrict__ mixl, float* __restrict__ out,
        float* __restrict__ drift_out, float* __restrict__ rep_out) {
    int bid  = blockIdx.x;
    int tid  = threadIdx.x;
    int lane = tid & 63;
    int wid  = tid >> 6;

    int t    = bid >> 6;                       // 64 blocks per t
    int i    = (bid >> 5) & 1;                 // uniform per block
    int rblk = ((bid & 63) << 4) + (wid << 2); // first of 4 rows within t

    __shared__ float PP[12];
    if (tid == 0) {
        Params P0, P1;
        compute_params(means, covs, bsr, t, i, 0, P0);
        compute_params(means, covs, bsr, t, i, 1, P1);
        PP[0] = P0.im00; PP[1] = 2.0f * P0.im01; PP[2] = P0.im11;
        PP[3] = P0.dr0;  PP[4] = P0.dr1;  PP[5] = P0.sc * __expf(P0.nldh);
        PP[6] = P1.im00; PP[7] = 2.0f * P1.im01; PP[8] = P1.im11;
        PP[9] = P1.dr0;  PP[10] = P1.dr1; PP[11] = P1.sc * __expf(P1.nldh);
    }
    __syncthreads();

    float m000 = PP[0], tm010 = PP[1], m110 = PP[2];
    float dr00 = PP[3], dr10 = PP[4];
    float sE0  = PP[5];
    float m001 = PP[6], tm011 = PP[7], m111 = PP[8];
    float dr01 = PP[9], dr11 = PP[10];
    float sE1  = PP[11];

    float mix = 1.0f / (1.0f + __expf(-mixl[0]));

    float bx[16], by[16], Qb[16];
#pragma unroll
    for (int q = 0; q < 4; ++q) {
        int b0 = (q * 256 + lane * 4) & 511;
        float4 sb01 = *(const float4*)(site + b0 * 2);
        float4 sb23 = *(const float4*)(site + b0 * 2 + 4);
        bx[q * 4 + 0] = sb01.x; by[q * 4 + 0] = sb01.y;
        bx[q * 4 + 1] = sb01.z; by[q * 4 + 1] = sb01.w;
        bx[q * 4 + 2] = sb23.x; by[q * 4 + 2] = sb23.y;
        bx[q * 4 + 3] = sb23.z; by[q * 4 + 3] = sb23.w;
        float m00 = (q < 2) ? m000 : m001;
        float tm01 = (q < 2) ? tm010 : tm011;
        float m11 = (q < 2) ? m110 : m111;
#pragma unroll
        for (int m = 0; m < 4; ++m) {
            int k = q * 4 + m;
            Qb[k] = m00 * bx[k] * bx[k] + tm01 * bx[k] * by[k] + m11 * by[k] * by[k];
        }
    }

    int abase = rblk & 511;
    float4 sa01 = *(const float4*)(site + abase * 2);
    float4 sa23 = *(const float4*)(site + abase * 2 + 4);
    float sax[4] = {sa01.x, sa01.z, sa23.x, sa23.z};
    float say[4] = {sa01.y, sa01.w, sa23.y, sa23.w};

#pragma unroll 1
    for (int rr = 0; rr < 4; ++rr) {
        int arow = rblk + rr;
        int a = abase + rr;
        float sa0 = sax[rr], sa1 = say[rr];

        float ra0 = sa0 - dr00, ra1 = sa1 - dr10;
        float c00 = m000 * ra0 * ra0 + tm010 * ra0 * ra1 + m110 * ra1 * ra1;
        float c10 = -(2.0f * m000 * ra0 + tm010 * ra1);
        float c20 = -(tm010 * ra0 + 2.0f * m110 * ra1);
        float rb0 = sa0 - dr01, rb1 = sa1 - dr11;
        float c01 = m001 * rb0 * rb0 + tm011 * rb0 * rb1 + m111 * rb1 * rb1;
        float c11 = -(2.0f * m001 * rb0 + tm011 * rb1);
        float c21 = -(tm011 * rb0 + 2.0f * m111 * rb1);

        float e[16];
        float p0 = 0.0f, p1 = 0.0f;
#pragma unroll
        for (int q = 0; q < 4; ++q) {
            float c0 = (q < 2) ? c00 : c01;
            float c1 = (q < 2) ? c10 : c11;
            float c2 = (q < 2) ? c20 : c21;
            float acc = 0.0f;
#pragma unroll
            for (int m = 0; m < 4; ++m) {
                int k = q * 4 + m;
                float qd = c0 + Qb[k];
                qd = fmaf(c1, bx[k], qd);
                qd = fmaf(c2, by[k], qd);
                float ev = __expf(-qd);
                e[k] = ev;
                acc += ev;
            }
            if (q < 2) p0 += acc; else p1 += acc;
        }

        float partial = sE0 * p0 + sE1 * p1;
#pragma unroll
        for (int off = 32; off; off >>= 1)
            partial += __shfl_xor(partial, off, 64);
        float s = partial;

        float r1 = fmaxf(s, JITTER);
        float s1 = s / r1;
        float r2 = fmaxf(s1, JITTER);
        float s2 = s1 / r2;
        float s3 = (1.0f - mix) * s2 + mix;
        float r3 = fmaxf(s3, JITTER);
        float f = (1.0f - mix) / (r1 * r2 * r3);
        float diagadd = mix / r3;
        float f0 = f * sE0, f1 = f * sE1;

        int diagcol = i * 512 + a;
        float* orow = out + ((size_t)t * 1024 + (size_t)arow) * 1024;

#pragma unroll
        for (int q = 0; q < 4; ++q) {
            int g0 = q * 256 + lane * 4;
            float ff = (q < 2) ? f0 : f1;
            float vv[4];
#pragma unroll
            for (int m = 0; m < 4; ++m) {
                float v = e[q * 4 + m] * ff;
                if ((g0 + m) == diagcol) v += diagadd;
                vv[m] = v;
            }
            float4 o = {vv[0], vv[1], vv[2], vv[3]};
            *(float4*)(orow + g0) = o;   // plain store: allocate in L2/L3
        }
    }

    if (bid == 0 && tid < 128) {
        int tt = tid >> 2, ii = (tid >> 1) & 1, jj = tid & 1;
        Params Q;
        compute_params(means, covs, bsr, tt, ii, jj, Q);
        drift_out[tid * 2 + 0] = Q.dr0;
        drift_out[tid * 2 + 1] = Q.dr1;
        rep_out[tid * 4 + 0] = Q.repA;
        rep_out[tid * 4 + 1] = Q.repB;
        rep_out[tid * 4 + 2] = Q.repB;
        rep_out[tid * 4 + 3] = Q.repD;
    }
}

extern "C" void kernel_launch(void* const* d_in, const int* in_sizes, int n_in,
                              void* d_out, int out_size, void* d_ws, size_t ws_size,
                              hipStream_t stream) {
    const float* means = (const float*)d_in[0];
    const float* covs  = (const float*)d_in[1];
    const float* site  = (const float*)d_in[2];
    const float* bsr   = (const float*)d_in[3];
    const float* mixl  = (const float*)d_in[4];
    float* out = (float*)d_out;

    const size_t TRANS = 32ull * 1024 * 1024; // 33,554,432
    float* drift_out = out + TRANS;           // 256 floats
    float* rep_out   = out + TRANS + 256;     // 512 floats

    // PROBE: store-only floor measurement (real kernel overwrites all bytes).
    fill_probe_kernel<<<2048, 256, 0, stream>>>((float4*)out, (int)(TRANS / 4));
    row4_fused_kernel<<<2048, 256, 0, stream>>>(means, covs, site, bsr, mixl,
                                                out, drift_out, rep_out);
}

// Round 17
// 29.561 us; speedup vs baseline: 1.7413x; 1.7413x over previous
//
#include <hip/hip_runtime.h>
#include <math.h>

#define CLIPV 1.0e4f
#define DT 0.1f
#define JITTER 1.0e-5f
#define MIN_SCALE 1.0e-4f

// nan_to_num(nan=0, posinf=CLIP, neginf=-CLIP) then clip(-CLIP, CLIP)
__device__ __forceinline__ float sanv(float x) {
    if (__builtin_isnan(x)) return 0.0f;
    return fminf(fmaxf(x, -CLIPV), CLIPV);
}

struct Params {
    float im00, im01, im11;   // sanitized inverse entries
    float nldh;               // -0.5 * log_det
    float dr0, dr1;           // sanitized drift
    float sc;                 // softplus(bsr) + MIN_SCALE
    float repA, repB, repD;   // repaired matrix (for output 3)
};

// Exact reference semantics for the per-(t,i,j) block parameters.
__device__ void compute_params(
        const float* __restrict__ means, const float* __restrict__ covs,
        const float* __restrict__ bsr, int t, int i, int j, Params& O) {
    float mi0 = sanv(means[(t * 2 + i) * 2 + 0]);
    float mi1 = sanv(means[(t * 2 + i) * 2 + 1]);
    float d0, d1;
    if (i == j) { d0 = DT * mi0; d1 = DT * mi1; }
    else {
        float mj0 = sanv(means[(t * 2 + j) * 2 + 0]);
        float mj1 = sanv(means[(t * 2 + j) * 2 + 1]);
        d0 = DT * (mi0 - mj0); d1 = DT * (mi1 - mj1);
    }
    O.dr0 = sanv(d0); O.dr1 = sanv(d1);

    const float* pi = covs + (t * 2 + i) * 4;
    float ra = sanv(pi[0]);
    float rb = 0.5f * (sanv(pi[1]) + sanv(pi[2]));
    float rd = sanv(pi[3]);
    if (i != j) {
        const float* pj = covs + (t * 2 + j) * 4;
        ra += sanv(pj[0]);
        rb += 0.5f * (sanv(pj[1]) + sanv(pj[2]));
        rd += sanv(pj[3]);
    }
    const float c2 = 2.0f * DT * DT;
    float A = sanv(1.0f + c2 * ra + JITTER);
    float B = sanv(c2 * rb);
    float D = sanv(1.0f + c2 * rd + JITTER);

    float diag_scale = fmaxf(0.5f * (fabsf(A) + fabsf(D)), 1.0f);
    const float j0 = 1e-5f; // max(JITTER, 1e-6)
    float invA = 0.f, invB = 0.f, invD = 0.f, logdet = 0.f;
    float repA = 0.f, repB = 0.f, repD = 0.f;
    bool found = false;
    float jit = j0;
    for (int k = 0; k < 8; ++k) {
        float add = jit * diag_scale;
        float a = sanv(A + add), b = B, d = sanv(D + add);
        float det = a * d - b * b;   // chol PD test for 2x2: a>0 && det>0
        if (a > 0.0f && det > 0.0f && __builtin_isfinite(det)) {
            repA = a; repB = b; repD = d;
            logdet = logf(det);      // == 2*sum(log(diag(chol)))
            float rdet = 1.0f / det;
            invA = sanv(d * rdet); invB = sanv(-b * rdet); invD = sanv(a * rdet);
            found = true;
            break;
        }
        jit *= 10.0f;
    }
    if (!found) {
        float jfin = j0 * 1.0e8f; // j0 * 10^MAX_TRIES
        float add = jfin * diag_scale;
        float sd0 = fmaxf(fabsf(A), add + 1e-4f);
        float sd1 = fmaxf(fabsf(D), add + 1e-4f);
        repA = sanv(sd0 + add); repB = 0.0f; repD = sanv(sd1 + add);
        float dfb0 = fmaxf(repA, 1e-6f), dfb1 = fmaxf(repD, 1e-6f);
        invA = sanv(1.0f / dfb0); invB = 0.0f; invD = sanv(1.0f / dfb1);
        logdet = logf(dfb0) + logf(dfb1);
    }
    if (__builtin_isnan(logdet)) logdet = 0.0f;
    else if (__builtin_isinf(logdet)) logdet = logdet > 0.0f ? 20.0f : -20.0f;

    float x = bsr[i * 2 + j];
    float sp = fmaxf(x, 0.0f) + log1pf(expf(-fabsf(x)));
    O.sc = sp + MIN_SCALE;
    O.im00 = invA; O.im01 = invB; O.im11 = invD;
    O.nldh = -0.5f * logdet;
    O.repA = repA; O.repB = repB; O.repD = repD;
}

// ---------------- Fused: one wave per FOUR consecutive rows ---------------
// 2048 blocks x 256 thr. Thread 0 computes the block's two (t,i,j) param
// sets into LDS (exact reference semantics); one barrier; all waves read.
// Factored quadratic: quad(row,b) = c0 + c1*bx + c2*by + Q(b), Q per wave.
// Plain allocating float4 stores (nt-store A/B'd worse in R13).
__global__ __launch_bounds__(256) void row4_fused_kernel(
        const float* __restrict__ means, const float* __restrict__ covs,
        const float* __restrict__ site, const float* __restrict__ bsr,
        const float* __restrict__ mixl, float* __restrict__ out,
        float* __restrict__ drift_out, float* __restrict__ rep_out) {
    int bid  = blockIdx.x;
    int tid  = threadIdx.x;
    int lane = tid & 63;
    int wid  = tid >> 6;

    int t    = bid >> 6;                       // 64 blocks per t
    int i    = (bid >> 5) & 1;                 // uniform per block
    int rblk = ((bid & 63) << 4) + (wid << 2); // first of 4 rows within t

    __shared__ float PP[12];
    if (tid == 0) {
        Params P0, P1;
        compute_params(means, covs, bsr, t, i, 0, P0);
        compute_params(means, covs, bsr, t, i, 1, P1);
        PP[0] = P0.im00; PP[1] = 2.0f * P0.im01; PP[2] = P0.im11;
        PP[3] = P0.dr0;  PP[4] = P0.dr1;  PP[5] = P0.sc * __expf(P0.nldh);
        PP[6] = P1.im00; PP[7] = 2.0f * P1.im01; PP[8] = P1.im11;
        PP[9] = P1.dr0;  PP[10] = P1.dr1; PP[11] = P1.sc * __expf(P1.nldh);
    }
    __syncthreads();

    float m000 = PP[0], tm010 = PP[1], m110 = PP[2];
    float dr00 = PP[3], dr10 = PP[4];
    float sE0  = PP[5];
    float m001 = PP[6], tm011 = PP[7], m111 = PP[8];
    float dr01 = PP[9], dr11 = PP[10];
    float sE1  = PP[11];

    float mix = 1.0f / (1.0f + __expf(-mixl[0]));

    // site-b coords for this lane's 16 columns + row-independent Q(b)
    float bx[16], by[16], Qb[16];
#pragma unroll
    for (int q = 0; q < 4; ++q) {
        int b0 = (q * 256 + lane * 4) & 511;
        float4 sb01 = *(const float4*)(site + b0 * 2);
        float4 sb23 = *(const float4*)(site + b0 * 2 + 4);
        bx[q * 4 + 0] = sb01.x; by[q * 4 + 0] = sb01.y;
        bx[q * 4 + 1] = sb01.z; by[q * 4 + 1] = sb01.w;
        bx[q * 4 + 2] = sb23.x; by[q * 4 + 2] = sb23.y;
        bx[q * 4 + 3] = sb23.z; by[q * 4 + 3] = sb23.w;
        float m00 = (q < 2) ? m000 : m001;
        float tm01 = (q < 2) ? tm010 : tm011;
        float m11 = (q < 2) ? m110 : m111;
#pragma unroll
        for (int m = 0; m < 4; ++m) {
            int k = q * 4 + m;
            Qb[k] = m00 * bx[k] * bx[k] + tm01 * bx[k] * by[k] + m11 * by[k] * by[k];
        }
    }

    // row-a coords for the 4 rows (contiguous 8 floats, 32B aligned)
    int abase = rblk & 511;
    float4 sa01 = *(const float4*)(site + abase * 2);
    float4 sa23 = *(const float4*)(site + abase * 2 + 4);
    float sax[4] = {sa01.x, sa01.z, sa23.x, sa23.z};
    float say[4] = {sa01.y, sa01.w, sa23.y, sa23.w};

#pragma unroll 1
    for (int rr = 0; rr < 4; ++rr) {
        int arow = rblk + rr;
        int a = abase + rr;
        float sa0 = sax[rr], sa1 = say[rr];

        // per-row linear coefficients, per j
        float ra0 = sa0 - dr00, ra1 = sa1 - dr10;
        float c00 = m000 * ra0 * ra0 + tm010 * ra0 * ra1 + m110 * ra1 * ra1;
        float c10 = -(2.0f * m000 * ra0 + tm010 * ra1);
        float c20 = -(tm010 * ra0 + 2.0f * m110 * ra1);
        float rb0 = sa0 - dr01, rb1 = sa1 - dr11;
        float c01 = m001 * rb0 * rb0 + tm011 * rb0 * rb1 + m111 * rb1 * rb1;
        float c11 = -(2.0f * m001 * rb0 + tm011 * rb1);
        float c21 = -(tm011 * rb0 + 2.0f * m111 * rb1);

        float e[16];
        float p0 = 0.0f, p1 = 0.0f;
#pragma unroll
        for (int q = 0; q < 4; ++q) {
            float c0 = (q < 2) ? c00 : c01;
            float c1 = (q < 2) ? c10 : c11;
            float c2 = (q < 2) ? c20 : c21;
            float acc = 0.0f;
#pragma unroll
            for (int m = 0; m < 4; ++m) {
                int k = q * 4 + m;
                float qd = c0 + Qb[k];
                qd = fmaf(c1, bx[k], qd);
                qd = fmaf(c2, by[k], qd);
                float ev = __expf(-qd);
                e[k] = ev;
                acc += ev;
            }
            if (q < 2) p0 += acc; else p1 += acc;
        }

        float partial = sE0 * p0 + sE1 * p1;
#pragma unroll
        for (int off = 32; off; off >>= 1)
            partial += __shfl_xor(partial, off, 64);
        float s = partial;

        // collapsed 3-stage normalization (finite positive sums)
        float r1 = fmaxf(s, JITTER);
        float s1 = s / r1;
        float r2 = fmaxf(s1, JITTER);
        float s2 = s1 / r2;
        float s3 = (1.0f - mix) * s2 + mix;
        float r3 = fmaxf(s3, JITTER);
        float f = (1.0f - mix) / (r1 * r2 * r3);
        float diagadd = mix / r3;
        float f0 = f * sE0, f1 = f * sE1;

        int diagcol = i * 512 + a;
        float* orow = out + ((size_t)t * 1024 + (size_t)arow) * 1024;

#pragma unroll
        for (int q = 0; q < 4; ++q) {
            int g0 = q * 256 + lane * 4;
            float ff = (q < 2) ? f0 : f1;
            float vv[4];
#pragma unroll
            for (int m = 0; m < 4; ++m) {
                float v = e[q * 4 + m] * ff;
                if ((g0 + m) == diagcol) v += diagadd;
                vv[m] = v;
            }
            float4 o = {vv[0], vv[1], vv[2], vv[3]};
            *(float4*)(orow + g0) = o;   // plain store: allocate in L2/L3
        }
    }

    // outputs 2 & 3: drift [32,2,2,2] and repaired [32,2,2,2,2] (block 0, tail)
    if (bid == 0 && tid < 128) {
        int tt = tid >> 2, ii = (tid >> 1) & 1, jj = tid & 1;
        Params Q;
        compute_params(means, covs, bsr, tt, ii, jj, Q);
        drift_out[tid * 2 + 0] = Q.dr0;
        drift_out[tid * 2 + 1] = Q.dr1;
        rep_out[tid * 4 + 0] = Q.repA;
        rep_out[tid * 4 + 1] = Q.repB;
        rep_out[tid * 4 + 2] = Q.repB;
        rep_out[tid * 4 + 3] = Q.repD;
    }
}

extern "C" void kernel_launch(void* const* d_in, const int* in_sizes, int n_in,
                              void* d_out, int out_size, void* d_ws, size_t ws_size,
                              hipStream_t stream) {
    const float* means = (const float*)d_in[0];
    const float* covs  = (const float*)d_in[1];
    const float* site  = (const float*)d_in[2];
    const float* bsr   = (const float*)d_in[3];
    const float* mixl  = (const float*)d_in[4];
    float* out = (float*)d_out;

    const size_t TRANS = 32ull * 1024 * 1024; // 33,554,432
    float* drift_out = out + TRANS;           // 256 floats
    float* rep_out   = out + TRANS + 256;     // 512 floats

    row4_fused_kernel<<<2048, 256, 0, stream>>>(means, covs, site, bsr, mixl,
                                                out, drift_out, rep_out);
}